// Round 9
// baseline (156.560 us; speedup 1.0000x reference)
//
#include <hip/hip_runtime.h>
#include <math.h>

// Problem constants (S4Checkpointed): b=2, L=2048, d=768, n=16, r=48
#define BATCH 2
#define LSEQ  2048
#define DIM   768
#define NST   16
#define RDT   48
#define BL    (BATCH*LSEQ)   // 4096
#define NCHUNK 32
#define CLEN   (LSEQ/NCHUNK) // 64
#define CPAD   68            // chunk stride floats: 68%32==4 -> wave's 4 groups on distinct banks
#define NPACK  (CLEN/4)      // 16 float4 packs per chunk
#define LP4    (LSEQ/4)      // 512 t-packs per (b)
#define L2E    1.4426950408889634f

typedef __attribute__((ext_vector_type(8))) short short8;     // 8 bf16 (4 VGPRs)
typedef __attribute__((ext_vector_type(4))) float float4e;    // MFMA acc

__device__ __forceinline__ ushort f2bf(float f) {
    union { float f; unsigned u; } v; v.f = f;
    unsigned u = v.u;
    u += 0x7fffu + ((u >> 16) & 1u);   // round-to-nearest-even
    return (ushort)(u >> 16);
}

// DPP cross-lane add on the VALU pipe (no ds_swizzle).
// 0xB1 = quad_perm(1,0,3,2) = xor1; 0x4E = quad_perm(2,3,0,1) = xor2;
// 0x124/0x128 = row_ror:4/8 (rotation mod 16 preserves n&3 -> exact for our sum).
template <int CTRL>
__device__ __forceinline__ float dpp_add(float v) {
    const int s = __builtin_amdgcn_update_dpp(__float_as_int(v), __float_as_int(v),
                                              CTRL, 0xF, 0xF, false);
    return v + __int_as_float(s);
}

// -------- Kernel P: x transpose (b,l,d)->(b,d,l) + pack W slice to bf16 ----
// grid (32, 13, 2): y<12 -> 64x64 tile transpose, float4 global both sides,
// coalesced stores (lanes span consecutive t). y==12 -> pack 80 live W rows.
__global__ __launch_bounds__(256) void pack_kernel(
        const float* __restrict__ x, const float* __restrict__ Wx,
        float* __restrict__ xT, ushort* __restrict__ Wbf) {
    if (blockIdx.y == DIM / 64) {
        const int blk = blockIdx.z * 32 + blockIdx.x;       // 0..63
        for (int idx = blk * 256 + threadIdx.x; idx < 80 * DIM; idx += 64 * 256) {
            const int j = idx / DIM;
            const int k = idx - j * DIM;
            const int row = (j < 16) ? j : ((j < 32) ? (j + 16) : (j + 1552));
            Wbf[idx] = f2bf(Wx[(size_t)row * DIM + k]);
        }
        return;
    }
    __shared__ float tile[64 * 65];   // stored transposed: tile[c][r]
    const int r0 = blockIdx.x * 64;   // l
    const int c0 = blockIdx.y * 64;   // d
    const int b  = blockIdx.z;
    const int tid = threadIdx.x;
    {
        const int c4 = tid & 15, rb = tid >> 4;
        #pragma unroll
        for (int rr = 0; rr < 4; ++rr) {
            const int row = rr * 16 + rb;
            const float4 v = *(const float4*)(x + ((size_t)b * LSEQ + r0 + row) * DIM + c0 + c4 * 4);
            tile[(c4 * 4 + 0) * 65 + row] = v.x;
            tile[(c4 * 4 + 1) * 65 + row] = v.y;
            tile[(c4 * 4 + 2) * 65 + row] = v.z;
            tile[(c4 * 4 + 3) * 65 + row] = v.w;
        }
    }
    __syncthreads();
    {
        const int t4 = tid & 15, dq = tid >> 4;
        #pragma unroll
        for (int pass = 0; pass < 4; ++pass) {
            const int dd = pass * 16 + dq;
            float4 v;
            v.x = tile[dd * 65 + t4 * 4 + 0];
            v.y = tile[dd * 65 + t4 * 4 + 1];
            v.z = tile[dd * 65 + t4 * 4 + 2];
            v.w = tile[dd * 65 + t4 * 4 + 3];
            *(float4*)(xT + ((size_t)b * DIM + c0 + dd) * LSEQ + r0 + t4 * 4) = v;
        }
    }
}

// -------- Kernel G: proj GEMM via MFMA, fp32 x read + in-register bf16 cvt --
// M=4096 (bl), N=80 (16 B | 16 C | 48 dt), K=768. One wave per 16-row tile;
// 5 N-tiles x 24 K-iters of mfma_f32_16x16x32_bf16. C/D layout (row=quad*4+reg,
// col=lane&15) lands exactly on pack-transposed Bpk/Cpk + dtpT rows.
__global__ __launch_bounds__(64) void proj_gemm_kernel(
        const float* __restrict__ x, const ushort* __restrict__ Wbf,
        float* __restrict__ Bpk, float* __restrict__ Cpk,
        float* __restrict__ dtpT) {
    const int m0   = blockIdx.x * 16;   // bl tile base (never straddles b)
    const int lane = threadIdx.x;       // 0..63
    const int col  = lane & 15;
    const int quad = lane >> 4;

    const float* A  = x + (size_t)(m0 + col) * DIM + quad * 8;
    const short* Bw = (const short*)Wbf;

    float4e acc[5] = {};
    #pragma unroll 4
    for (int kk = 0; kk < 24; ++kk) {
        const float4 a0 = *(const float4*)(A + kk * 32);
        const float4 a1 = *(const float4*)(A + kk * 32 + 4);
        short8 a;
        a[0] = (short)f2bf(a0.x); a[1] = (short)f2bf(a0.y);
        a[2] = (short)f2bf(a0.z); a[3] = (short)f2bf(a0.w);
        a[4] = (short)f2bf(a1.x); a[5] = (short)f2bf(a1.y);
        a[6] = (short)f2bf(a1.z); a[7] = (short)f2bf(a1.w);
        #pragma unroll
        for (int nt = 0; nt < 5; ++nt) {
            const short8 bf = *(const short8*)(Bw + (size_t)(nt * 16 + col) * DIM + kk * 32 + quad * 8);
            acc[nt] = __builtin_amdgcn_mfma_f32_16x16x32_bf16(a, bf, acc[nt], 0, 0, 0);
        }
    }

    const int b  = m0 >> 11;
    const int t0 = m0 & 2047;
    const size_t pk4 = ((size_t)(b * LP4 + (t0 >> 2) + quad)) * NST + col;
    ((float4*)Bpk)[pk4] = *(float4*)&acc[0];
    ((float4*)Cpk)[pk4] = *(float4*)&acc[1];
    #pragma unroll
    for (int nt = 2; nt < 5; ++nt) {
        const int r = (nt - 2) * 16 + col;
        *(float4*)(dtpT + ((size_t)(b * RDT + r)) * LSEQ + t0 + quad * 4) = *(float4*)&acc[nt];
    }
}

// -------- Kernel T: 64x64 tiled transpose (b,R,C)->(b,C,R), coalesced ------
__global__ __launch_bounds__(256) void xpose_kernel(
        const float* __restrict__ in, float* __restrict__ out, int R, int C) {
    __shared__ float tile[64 * 65];   // transposed: tile[c][r]
    const int r0 = blockIdx.x * 64;
    const int c0 = blockIdx.y * 64;
    const int b  = blockIdx.z;
    const int tid = threadIdx.x;
    {
        const int c4 = tid & 15, rb = tid >> 4;
        #pragma unroll
        for (int rr = 0; rr < 4; ++rr) {
            const int row = rr * 16 + rb;
            const float4 v = *(const float4*)(in + ((size_t)b * R + r0 + row) * C + c0 + c4 * 4);
            tile[(c4 * 4 + 0) * 65 + row] = v.x;
            tile[(c4 * 4 + 1) * 65 + row] = v.y;
            tile[(c4 * 4 + 2) * 65 + row] = v.z;
            tile[(c4 * 4 + 3) * 65 + row] = v.w;
        }
    }
    __syncthreads();
    {
        const int t4 = tid & 15, dq = tid >> 4;
        #pragma unroll
        for (int pass = 0; pass < 4; ++pass) {
            const int dd = pass * 16 + dq;
            float4 v;
            v.x = tile[dd * 65 + t4 * 4 + 0];
            v.y = tile[dd * 65 + t4 * 4 + 1];
            v.z = tile[dd * 65 + t4 * 4 + 2];
            v.w = tile[dd * 65 + t4 * 4 + 3];
            *(float4*)(out + ((size_t)b * C + c0 + dd) * R + r0 + t4 * 4) = v;
        }
    }
}

// -------- Kernel C: fused delta + chunked scan (pack-trick, Kogge-Stone,
//          DPP n-reduction on the VALU pipe) --------------------------------
// One block (512 thr) per (b,d); 32 groups x 16 n-lanes; group g owns 64 t.
__global__ __launch_bounds__(512) void scan_kernel(
        const float* __restrict__ xT, const float* __restrict__ z,
        const float* __restrict__ A_log, const float* __restrict__ Dp,
        const float* __restrict__ Bpk, const float* __restrict__ Cpk,
        const float* __restrict__ dtpT, const float* __restrict__ Wdt,
        const float* __restrict__ bdt, float* __restrict__ yT) {
    __shared__ float sdel[NCHUNK * CPAD];   // delta; phase 3 reuses as y buffer
    __shared__ float sdlx[NCHUNK * CPAD];   // delta*x
    __shared__ float sx[NCHUNK * CPAD];     // x (for D-term in epilogue)
    __shared__ float sP[NCHUNK][NST];
    __shared__ float sq[NCHUNK][NST];
    __shared__ float sw[RDT];

    const int tid = threadIdx.x;
    const int ch = blockIdx.x;           // b*768 + d
    const int b = ch / DIM;
    const int d = ch % DIM;
    const size_t row = (size_t)ch * LSEQ;

    // ---- phase 0a: stage x row (padded chunks) + Wdt row to LDS
    if (tid < RDT) sw[tid] = Wdt[(size_t)d * RDT + tid];
    const float4 xv4 = ((const float4*)(xT + row))[tid];
    ((float4*)sx)[(tid >> 4) * (CPAD / 4) + (tid & 15)] = xv4;
    __syncthreads();

    // ---- phase 0b: fused delta -> sdel, delta*x -> sdlx
    {
        const float bb = 2.0f * bdt[d];
        const float* dbase = dtpT + (size_t)b * RDT * LSEQ;
        float4 acc = make_float4(bb, bb, bb, bb);
        #pragma unroll 3
        for (int k4 = 0; k4 < RDT / 4; ++k4) {
            const float4 wv = ((const float4*)sw)[k4];
            #pragma unroll
            for (int j = 0; j < 4; ++j) {
                const int k = k4 * 4 + j;
                const float wk = (j == 0) ? wv.x : (j == 1) ? wv.y : (j == 2) ? wv.z : wv.w;
                const float4 v = ((const float4*)(dbase + (size_t)k * LSEQ))[tid];
                acc.x = fmaf(v.x, wk, acc.x);
                acc.y = fmaf(v.y, wk, acc.y);
                acc.z = fmaf(v.z, wk, acc.z);
                acc.w = fmaf(v.w, wk, acc.w);
            }
        }
        float4 sp;
        sp.x = (acc.x > 20.f) ? acc.x : __logf(1.f + __expf(acc.x));
        sp.y = (acc.y > 20.f) ? acc.y : __logf(1.f + __expf(acc.y));
        sp.z = (acc.z > 20.f) ? acc.z : __logf(1.f + __expf(acc.z));
        sp.w = (acc.w > 20.f) ? acc.w : __logf(1.f + __expf(acc.w));
        const int sidx = (tid >> 4) * (CPAD / 4) + (tid & 15);
        ((float4*)sdel)[sidx] = sp;
        ((float4*)sdlx)[sidx] = make_float4(sp.x * xv4.x, sp.y * xv4.y,
                                            sp.z * xv4.z, sp.w * xv4.w);
    }
    __syncthreads();

    const int g = tid >> 4;          // chunk 0..31
    const int n = tid & 15;          // state index
    const float Aln2 = -__expf(A_log[d * NST + n]) * L2E;  // exp(x)=exp2(x*L2E)
    const float4* Bg = (const float4*)Bpk + ((size_t)(b * LP4 + g * NPACK) * NST + n);
    const float4* Cg = (const float4*)Cpk + ((size_t)(b * LP4 + g * NPACK) * NST + n);
    const float* dchunk  = sdel + g * CPAD;
    const float* uxchunk = sdlx + g * CPAD;

    // ---- phase 1: local scan with pack trick (chain: 1 fma per 4t)
    {
        float h = 0.f, Ptot = 1.f;
        float4 Bn_ = Bg[0];
        #pragma unroll 4
        for (int p = 0; p < NPACK; ++p) {
            const float4 B4 = Bn_;
            if (p < NPACK - 1) Bn_ = Bg[(p + 1) * NST];
            const float4 dl = *(const float4*)(dchunk + 4 * p);
            const float4 ux = *(const float4*)(uxchunk + 4 * p);
            const float u0 = ux.x * B4.x, u1 = ux.y * B4.y;
            const float u2 = ux.z * B4.z, u3 = ux.w * B4.w;
            const float e0  = __builtin_amdgcn_exp2f(Aln2 * dl.x);
            const float dA1 = __builtin_amdgcn_exp2f(Aln2 * dl.y);
            const float dA2 = __builtin_amdgcn_exp2f(Aln2 * dl.z);
            const float dA3 = __builtin_amdgcn_exp2f(Aln2 * dl.w);
            float s = u0;
            s = fmaf(dA1, s, u1); s = fmaf(dA2, s, u2); s = fmaf(dA3, s, u3);
            const float E3 = ((e0 * dA1) * (dA2 * dA3));
            h = fmaf(E3, h, s);          // the only cross-pack chain op
            Ptot *= E3;
        }
        sP[g][n] = Ptot;
        sq[g][n] = h;
    }
    __syncthreads();

    // ---- phase 2: Kogge-Stone inclusive scan of transforms over chunks
    {
        float Pc = sP[g][n], qc = sq[g][n];
        #pragma unroll
        for (int s = 1; s < NCHUNK; s <<= 1) {
            float Pp = 1.f, qp = 0.f;
            if (g >= s) { Pp = sP[g - s][n]; qp = sq[g - s][n]; }
            __syncthreads();
            qc = fmaf(Pc, qp, qc);
            Pc *= Pp;
            sP[g][n] = Pc; sq[g][n] = qc;
            __syncthreads();
        }
    }

    // ---- phase 3: re-scan with carry; DPP reduction over n (VALU pipe)
    {
        float h = (g == 0) ? 0.f : sq[g - 1][n];
        float* ybuf = sdel;              // reuse: pack p written after pack p read
        float4 Bn_ = Bg[0];
        float4 Cn_ = Cg[0];
        #pragma unroll 4
        for (int p = 0; p < NPACK; ++p) {
            const float4 B4 = Bn_, C4 = Cn_;
            if (p < NPACK - 1) { Bn_ = Bg[(p + 1) * NST]; Cn_ = Cg[(p + 1) * NST]; }
            const float4 dl = *(const float4*)(dchunk + 4 * p);
            const float4 ux = *(const float4*)(uxchunk + 4 * p);
            const float u0 = ux.x * B4.x, u1 = ux.y * B4.y;
            const float u2 = ux.z * B4.z, u3 = ux.w * B4.w;
            const float E0  = __builtin_amdgcn_exp2f(Aln2 * dl.x);
            const float dA1 = __builtin_amdgcn_exp2f(Aln2 * dl.y);
            const float dA2 = __builtin_amdgcn_exp2f(Aln2 * dl.z);
            const float dA3 = __builtin_amdgcn_exp2f(Aln2 * dl.w);
            const float E1 = E0 * dA1, E2 = E1 * dA2, E3 = E2 * dA3;
            const float s0 = u0;
            const float s1 = fmaf(dA1, s0, u1);
            const float s2 = fmaf(dA2, s1, u2);
            const float s3 = fmaf(dA3, s2, u3);
            const float h0 = fmaf(E0, h, s0);
            const float h1 = fmaf(E1, h, s1);
            const float h2 = fmaf(E2, h, s2);
            const float h3 = fmaf(E3, h, s3);
            h = h3;                      // 1-fma cross-pack chain
            float p0 = h0 * C4.x, p1 = h1 * C4.y, p2 = h2 * C4.z, p3 = h3 * C4.w;
            p0 = dpp_add<0xB1>(p0); p0 = dpp_add<0x4E>(p0);   // quad sums
            p1 = dpp_add<0xB1>(p1); p1 = dpp_add<0x4E>(p1);
            p2 = dpp_add<0xB1>(p2); p2 = dpp_add<0x4E>(p2);
            p3 = dpp_add<0xB1>(p3); p3 = dpp_add<0x4E>(p3);
            float v = (n & 1) ? ((n & 2) ? p3 : p1) : ((n & 2) ? p2 : p0);
            v = dpp_add<0x124>(v);       // row_ror:4  (+lane n+4 mod 16)
            v = dpp_add<0x128>(v);       // row_ror:8  (+lane n+8 mod 16)
            if (n < 4) ybuf[g * CPAD + 4 * p + n] = v;   // D-term added in epilogue
        }
    }
    __syncthreads();

    // ---- epilogue: y = (ybuf + D*x) * silu(z), write yT (aliases xT)
    {
        const float Dd = Dp[d];
        const float* zrow = z + row;
        float* yrow = yT + row;
        const int t = tid * 4;
        const int idx = (t >> 6) * CPAD + (t & 63);      // 4-aligned within chunk
        const float4 yv = *(const float4*)(sdel + idx);
        const float4 xv = *(const float4*)(sx + idx);
        const float4 zv = ((const float4*)zrow)[tid];
        float4 o;
        o.x = fmaf(xv.x, Dd, yv.x) * zv.x / (1.f + __expf(-zv.x));
        o.y = fmaf(xv.y, Dd, yv.y) * zv.y / (1.f + __expf(-zv.y));
        o.z = fmaf(xv.z, Dd, yv.z) * zv.z / (1.f + __expf(-zv.z));
        o.w = fmaf(xv.w, Dd, yv.w) * zv.w / (1.f + __expf(-zv.w));
        ((float4*)yrow)[tid] = o;
    }
}

extern "C" void kernel_launch(void* const* d_in, const int* in_sizes, int n_in,
                              void* d_out, int out_size, void* d_ws, size_t ws_size,
                              hipStream_t stream) {
    const float* x     = (const float*)d_in[0];  // (2,2048,768)
    const float* z     = (const float*)d_in[1];  // (2,768,2048)
    const float* A_log = (const float*)d_in[2];  // (768,16)
    const float* D     = (const float*)d_in[3];  // (768,)
    const float* Wx    = (const float*)d_in[4];  // (1680,768)
    const float* Wdt   = (const float*)d_in[5];  // (768,48)
    const float* bdt   = (const float*)d_in[6];  // (768,)
    float* out = (float*)d_out;

    // ws layout (floats): Bpk | Cpk | dtpT | xT (scan writes yT over it) | Wbf(bf16)
    float* ws    = (float*)d_ws;
    float* Bpk   = ws;
    float* Cpk   = Bpk + (size_t)BATCH * LP4 * NST * 4;
    float* dtpT  = Cpk + (size_t)BATCH * LP4 * NST * 4;
    float* xT    = dtpT + (size_t)BATCH * RDT * LSEQ;
    float* yT    = xT;
    ushort* Wbf  = (ushort*)(xT + (size_t)BATCH * DIM * LSEQ);

    hipLaunchKernelGGL(pack_kernel, dim3(LSEQ / 64, DIM / 64 + 1, BATCH), dim3(256), 0, stream,
                       x, Wx, xT, Wbf);
    hipLaunchKernelGGL(proj_gemm_kernel, dim3(BL / 16), dim3(64), 0, stream,
                       x, Wbf, Bpk, Cpk, dtpT);
    hipLaunchKernelGGL(scan_kernel, dim3(BATCH * DIM), dim3(512), 0, stream,
                       xT, z, A_log, D, Bpk, Cpk, dtpT, Wdt, bdt, yT);
    hipLaunchKernelGGL(xpose_kernel, dim3(DIM / 64, LSEQ / 64, BATCH), dim3(256), 0, stream,
                       yT, out, DIM, LSEQ);
}